// Round 1
// baseline (554.794 us; speedup 1.0000x reference)
//
#include <hip/hip_runtime.h>

#define DD   256
#define TT   1024
#define BB   8
#define BT   8192
#define KK   8192
#define SPLITS 16
#define NSPLIT 512          // codes per split
#define TILE_M 128          // tokens per block
#define TILE_N 128          // codes per inner tile
#define CT     4            // NSPLIT / TILE_N
#define KC     32           // d-chunk
#define NKC    8            // DD / KC

#define ZQ_SIZE 2097152     // B*D*T

// ws layout in floats
#define ACC_OFF  0
#define A_OFF    256
#define C_OFF    (A_OFF + BT)
#define VAL_OFF  (C_OFF + KK)
#define IDX_OFF  (VAL_OFF + SPLITS*BT)
#define FIDX_OFF (IDX_OFF + SPLITS*BT)

#define FLT_INF 3.402823466e38f

// ---------------- kernel 1: row norms ----------------
__global__ __launch_bounds__(256) void vq_norms(const float* __restrict__ z,
                                                const float* __restrict__ cb,
                                                float* __restrict__ An,
                                                float* __restrict__ Cn) {
    if (blockIdx.x < 32) {
        // A[token] = sum_d z[b,d,t]^2 ; coalesced over t
        int g = blockIdx.x * 256 + threadIdx.x;      // 0..8191
        int b = g >> 10, t = g & 1023;
        const float* zp = z + (size_t)b * (DD * TT) + t;
        float s = 0.f;
        #pragma unroll 8
        for (int d = 0; d < DD; ++d) {
            float v = zp[d * TT];
            float v2 = v * v;              // match np: square rounded, then sum
            s = s + v2;
        }
        An[g] = s;
    } else {
        // C[code] = ||codebook row||^2, one wave per code
        int code = (blockIdx.x - 32) * 4 + (threadIdx.x >> 6);
        int lane = threadIdx.x & 63;
        float4 v = *(const float4*)&cb[(size_t)code * DD + lane * 4];
        float s = v.x * v.x + v.y * v.y + v.z * v.z + v.w * v.w;
        #pragma unroll
        for (int off = 32; off; off >>= 1) s += __shfl_down(s, off, 64);
        if (lane == 0) Cn[code] = s;
    }
}

// ---------------- kernel 2: fused distance GEMM + online argmin ----------------
__global__ __launch_bounds__(256, 4) void vq_scores(const float* __restrict__ z,
                                                    const float* __restrict__ cb,
                                                    const float* __restrict__ An,
                                                    const float* __restrict__ Cn,
                                                    float* __restrict__ ws_val,
                                                    int*   __restrict__ ws_idx) {
    __shared__ float Zs[KC][TILE_M];        // [d][token], no pad (conflict-free)
    __shared__ float Cs[KC][TILE_N + 4];    // [d][code], padded stride 132

    const int tid = threadIdx.x;
    const int ty = tid >> 4;       // 0..15 -> token octet
    const int tx = tid & 15;       // 0..15 -> code octet
    const int tile  = blockIdx.x & 63;
    const int split = blockIdx.x >> 6;
    const int token0 = tile * TILE_M;
    const int code0  = split * NSPLIT;
    const float* zb = z + (size_t)(token0 >> 10) * (DD * TT) + (token0 & 1023);

    float best[8];
    int   bidx[8];
    #pragma unroll
    for (int i = 0; i < 8; ++i) { best[i] = FLT_INF; bidx[i] = 0; }

    for (int ct = 0; ct < CT; ++ct) {
        const int cbase = code0 + ct * TILE_N;
        float acc[8][8];
        #pragma unroll
        for (int i = 0; i < 8; ++i)
            #pragma unroll
            for (int j = 0; j < 8; ++j) acc[i][j] = 0.f;

        for (int kc = 0; kc < NKC; ++kc) {
            __syncthreads();   // protect LDS from previous iteration's readers
            // stage Zs: 32 d-rows x 128 tokens (coalesced float4 over tokens)
            #pragma unroll
            for (int n = 0; n < 4; ++n) {
                int fid = n * 256 + tid;           // 0..1023
                int k = fid >> 5, c4 = fid & 31;
                float4 v = *(const float4*)&zb[(size_t)(kc * KC + k) * TT + c4 * 4];
                *(float4*)&Zs[k][c4 * 4] = v;
            }
            // stage Cs transposed: codebook rows -> [d][code]
            #pragma unroll
            for (int n = 0; n < 4; ++n) {
                int fid = n * 256 + tid;           // 0..1023
                int r = fid >> 3, c4 = fid & 7;
                float4 v = *(const float4*)&cb[(size_t)(cbase + r) * DD + kc * KC + c4 * 4];
                Cs[c4 * 4 + 0][r] = v.x;
                Cs[c4 * 4 + 1][r] = v.y;
                Cs[c4 * 4 + 2][r] = v.z;
                Cs[c4 * 4 + 3][r] = v.w;
            }
            __syncthreads();

            #pragma unroll 8
            for (int k = 0; k < KC; ++k) {
                float4 a0 = *(const float4*)&Zs[k][ty * 8];
                float4 a1 = *(const float4*)&Zs[k][ty * 8 + 4];
                float4 b0 = *(const float4*)&Cs[k][tx * 8];
                float4 b1 = *(const float4*)&Cs[k][tx * 8 + 4];
                float av[8] = {a0.x, a0.y, a0.z, a0.w, a1.x, a1.y, a1.z, a1.w};
                float bv[8] = {b0.x, b0.y, b0.z, b0.w, b1.x, b1.y, b1.z, b1.w};
                #pragma unroll
                for (int i = 0; i < 8; ++i)
                    #pragma unroll
                    for (int j = 0; j < 8; ++j)
                        acc[i][j] = fmaf(av[i], bv[j], acc[i][j]);
            }
        }

        // epilogue: distance = fl(fl(A - 2B) + C), online argmin (ascending code)
        float cv[8];
        #pragma unroll
        for (int j = 0; j < 8; ++j) cv[j] = Cn[cbase + tx * 8 + j];
        #pragma unroll
        for (int i = 0; i < 8; ++i) {
            float Ai = An[token0 + ty * 8 + i];
            #pragma unroll
            for (int j = 0; j < 8; ++j) {
                float d1 = fmaf(-2.f, acc[i][j], Ai);   // == fl(A - 2B): 2B exact
                float dist = d1 + cv[j];                 // fl(+C)
                int idx = cbase + tx * 8 + j;
                if (dist < best[i]) { best[i] = dist; bidx[i] = idx; }
            }
        }
    }

    // reduce across the 16 tx lanes (same wave, width-16 subgroups)
    #pragma unroll
    for (int off = 8; off; off >>= 1) {
        #pragma unroll
        for (int i = 0; i < 8; ++i) {
            float ov = __shfl_down(best[i], off, 16);
            int   oi = __shfl_down(bidx[i], off, 16);
            if (ov < best[i] || (ov == best[i] && oi < bidx[i])) {
                best[i] = ov; bidx[i] = oi;
            }
        }
    }
    if (tx == 0) {
        #pragma unroll
        for (int i = 0; i < 8; ++i) {
            int tok = token0 + ty * 8 + i;
            ws_val[split * BT + tok] = best[i];
            ws_idx[split * BT + tok] = bidx[i];
        }
    }
}

// ---------------- kernel 3: reduce splits -> final indices ----------------
__global__ __launch_bounds__(256) void vq_finalize(const float* __restrict__ ws_val,
                                                   const int* __restrict__ ws_idx,
                                                   int* __restrict__ fidx,
                                                   float* __restrict__ out_idx,
                                                   float* __restrict__ loss_acc) {
    int g = blockIdx.x * 256 + threadIdx.x;
    float bv = FLT_INF; int bi = 0;
    #pragma unroll
    for (int s = 0; s < SPLITS; ++s) {       // ascending code ranges: strict < keeps first
        float v = ws_val[s * BT + g];
        int  ix = ws_idx[s * BT + g];
        if (v < bv) { bv = v; bi = ix; }
    }
    fidx[g] = bi;
    out_idx[g] = (float)bi;                  // out buffer is fp32
    if (g == 0) *loss_acc = 0.f;
}

// ---------------- kernel 4: gather z_q, straight-through out, loss partial ----------------
__global__ __launch_bounds__(256) void vq_gather(const float* __restrict__ z,
                                                 const float* __restrict__ cb,
                                                 const int* __restrict__ fidx,
                                                 float* __restrict__ out,
                                                 float* __restrict__ loss_acc) {
    int e4 = blockIdx.x * 256 + threadIdx.x;     // float4 index, 524288 total
    int t4 = e4 & 255;
    int rest = e4 >> 8;
    int d = rest & 255;
    int b = rest >> 8;
    int gbase = b * 1024 + t4 * 4;

    int4 iv = *(const int4*)&fidx[gbase];
    float4 zv = *(const float4*)&z[(size_t)e4 * 4];

    float q0 = cb[(size_t)iv.x * DD + d];
    float q1 = cb[(size_t)iv.y * DD + d];
    float q2 = cb[(size_t)iv.z * DD + d];
    float q3 = cb[(size_t)iv.w * DD + d];

    float d0 = q0 - zv.x, d1 = q1 - zv.y, d2 = q2 - zv.z, d3 = q3 - zv.w;
    float4 o;                                    // replicate z + (z_q - z) rounding
    o.x = zv.x + d0; o.y = zv.y + d1; o.z = zv.z + d2; o.w = zv.w + d3;
    *(float4*)&out[(size_t)e4 * 4] = o;

    float s = d0 * d0 + d1 * d1 + d2 * d2 + d3 * d3;
    #pragma unroll
    for (int off = 32; off; off >>= 1) s += __shfl_down(s, off, 64);
    __shared__ float wsum[4];
    if ((threadIdx.x & 63) == 0) wsum[threadIdx.x >> 6] = s;
    __syncthreads();
    if (threadIdx.x == 0)
        atomicAdd(loss_acc, wsum[0] + wsum[1] + wsum[2] + wsum[3]);
}

// ---------------- kernel 5: finalize loss ----------------
__global__ void vq_loss(const float* __restrict__ loss_acc, float* __restrict__ out_loss) {
    *out_loss = 1.25f * (*loss_acc) / 2097152.f;
}

extern "C" void kernel_launch(void* const* d_in, const int* in_sizes, int n_in,
                              void* d_out, int out_size, void* d_ws, size_t ws_size,
                              hipStream_t stream) {
    const float* z  = (const float*)d_in[0];
    const float* cb = (const float*)d_in[1];
    float* out = (float*)d_out;
    float* ws  = (float*)d_ws;

    float* An      = ws + A_OFF;
    float* Cn      = ws + C_OFF;
    float* ws_val  = ws + VAL_OFF;
    int*   ws_idx  = (int*)(ws + IDX_OFF);
    int*   fidx    = (int*)(ws + FIDX_OFF);
    float* acc     = ws + ACC_OFF;

    vq_norms   <<<32 + KK / 4, 256, 0, stream>>>(z, cb, An, Cn);
    vq_scores  <<<64 * SPLITS, 256, 0, stream>>>(z, cb, An, Cn, ws_val, ws_idx);
    vq_finalize<<<BT / 256,    256, 0, stream>>>(ws_val, ws_idx, fidx, out + ZQ_SIZE, acc);
    vq_gather  <<<ZQ_SIZE / 1024, 256, 0, stream>>>(z, cb, fidx, out, acc);
    vq_loss    <<<1, 1, 0, stream>>>(acc, out + ZQ_SIZE + BT);
}